// Round 1
// baseline (766.690 us; speedup 1.0000x reference)
//
#include <hip/hip_runtime.h>
#include <stdint.h>

#define N_TOK 16384
#define DDIM  1024
#define NEXP  8

#define BM 128
#define BN 128
#define BK 32

typedef __bf16 bf16x8 __attribute__((ext_vector_type(8)));
typedef float  f32x4  __attribute__((ext_vector_type(4)));

__device__ __forceinline__ unsigned short f2bf(float f) {
  union { float f; uint32_t u; } a; a.f = f;
  uint32_t u = a.u;
  u += 0x7fffu + ((u >> 16) & 1u);   // RNE
  return (unsigned short)(u >> 16);
}

__device__ __forceinline__ void load_lds16(const void* g, void* l) {
  __builtin_amdgcn_global_load_lds(
      (const __attribute__((address_space(1))) void*)g,
      (__attribute__((address_space(3))) void*)l,
      16, 0, 0);
}

// ---- cast expert_w fp32 -> bf16 ----
__global__ __launch_bounds__(256) void cast_w_kernel(const float4* __restrict__ src,
                                                     ushort4* __restrict__ dst) {
  size_t i = (size_t)blockIdx.x * 256 + threadIdx.x;   // E*D*D/4 elements
  float4 v = src[i];
  dst[i] = make_ushort4(f2bf(v.x), f2bf(v.y), f2bf(v.z), f2bf(v.w));
}

// ---- router: logits, softmax, top2, binning, loss partials, x->bf16 ----
__global__ __launch_bounds__(256) void router_kernel(
    const float* __restrict__ x, const float* __restrict__ rw,
    const float* __restrict__ rb, const float* __restrict__ cv,
    const float* __restrict__ cwp,
    unsigned short* __restrict__ xg,
    int* __restrict__ perm_idx, float* __restrict__ perm_w,
    int* __restrict__ cnt, float* __restrict__ sum_w)
{
  __shared__ float sw[NEXP];
  if (threadIdx.x < NEXP) sw[threadIdx.x] = 0.0f;
  __syncthreads();

  const int wave = threadIdx.x >> 6;
  const int lane = threadIdx.x & 63;
  const int n = blockIdx.x * 4 + wave;

  float p[NEXP];
#pragma unroll
  for (int e = 0; e < NEXP; ++e) p[e] = 0.0f;

  const float2* x2 = (const float2*)(x + (size_t)n * DDIM);
  uint32_t* xgp = (uint32_t*)(xg + (size_t)n * DDIM);

#pragma unroll
  for (int i = 0; i < 8; ++i) {
    int dp = lane + 64 * i;
    float2 xv = x2[dp];
    xgp[dp] = (uint32_t)f2bf(xv.x) | ((uint32_t)f2bf(xv.y) << 16);
#pragma unroll
    for (int e = 0; e < NEXP; ++e) {
      float2 wv = ((const float2*)(rw + e * DDIM))[dp];
      p[e] = fmaf(xv.x, wv.x, fmaf(xv.y, wv.y, p[e]));
    }
  }
#pragma unroll
  for (int e = 0; e < NEXP; ++e) {
#pragma unroll
    for (int off = 32; off > 0; off >>= 1)
      p[e] += __shfl_xor(p[e], off, 64);
  }

  if (lane == 0) {
    float cw = cwp[0];
    float w[NEXP];
    float m = -1e30f;
#pragma unroll
    for (int e = 0; e < NEXP; ++e) {
      w[e] = p[e] + rb[e] + cw * cv[e];
      m = fmaxf(m, w[e]);
    }
    float s = 0.0f;
#pragma unroll
    for (int e = 0; e < NEXP; ++e) { w[e] = expf(w[e] - m); s += w[e]; }
    float inv = 1.0f / s;
#pragma unroll
    for (int e = 0; e < NEXP; ++e) { w[e] *= inv; atomicAdd(&sw[e], w[e]); }
    // top-2, ties -> lowest index (matches lax.top_k)
    int e0 = 0;
#pragma unroll
    for (int e = 1; e < NEXP; ++e) if (w[e] > w[e0]) e0 = e;
    int e1 = (e0 == 0) ? 1 : 0;
#pragma unroll
    for (int e = 0; e < NEXP; ++e) if (e != e0 && w[e] > w[e1]) e1 = e;
    float rsum = 1.0f / (w[e0] + w[e1]);
    int p0 = atomicAdd(&cnt[e0], 1);
    perm_idx[e0 * N_TOK + p0] = n;
    perm_w [e0 * N_TOK + p0] = w[e0] * rsum;
    int p1 = atomicAdd(&cnt[e1], 1);
    perm_idx[e1 * N_TOK + p1] = n;
    perm_w [e1 * N_TOK + p1] = w[e1] * rsum;
  }
  __syncthreads();
  if (threadIdx.x < NEXP) atomicAdd(&sum_w[threadIdx.x], sw[threadIdx.x]);
}

// ---- grouped GEMM: per-expert gathered tokens, bf16 MFMA, weighted scatter ----
__global__ __launch_bounds__(256) void moe_gemm_kernel(
    const unsigned short* __restrict__ xg, const unsigned short* __restrict__ wb,
    const float* __restrict__ eb,
    const int* __restrict__ perm_idx, const float* __restrict__ perm_w,
    const int* __restrict__ cnt, float* __restrict__ out)
{
  const int e = blockIdx.z;
  const int count = cnt[e];
  const int tm = blockIdx.y;
  if (tm * BM >= count) return;
  const int tn = blockIdx.x;

  __shared__ alignas(16) __bf16 As[BM * BK];
  __shared__ alignas(16) __bf16 Bs[BN * BK];
  __shared__ int   tokS[BM];
  __shared__ float wtS[BM];

  const int tid = threadIdx.x;
  const int wave = tid >> 6;
  const int lane = tid & 63;

  if (tid < BM) {
    int row = tm * BM + tid;
    int rc = row < count ? row : count - 1;
    tokS[tid] = perm_idx[e * N_TOK + rc];
    wtS[tid] = (row < count) ? perm_w[e * N_TOK + row] : 0.0f;
  }
  __syncthreads();

  // staging: each wave covers 32 rows via 2 lane-linear 16B calls of 16 rows.
  // chunk swizzle: chunk c of row m stored at slot c ^ ((m>>1)&3)  -> 2-way-max
  // bank pattern on the b128 fragment reads (free per m136).
  const int slot = lane & 3;
  const int ar0 = wave * 32 + (lane >> 2);
  const int ar1 = ar0 + 16;
  const int ac0 = slot ^ ((ar0 >> 1) & 3);
  const int ac1 = slot ^ ((ar1 >> 1) & 3);

  const unsigned short* aptr0 = xg + (size_t)tokS[ar0] * DDIM + ac0 * 8;
  const unsigned short* aptr1 = xg + (size_t)tokS[ar1] * DDIM + ac1 * 8;
  const unsigned short* wbase = wb + (size_t)e * DDIM * DDIM;
  const unsigned short* bptr0 = wbase + (size_t)(tn * BN + ar0) * DDIM + ac0 * 8;
  const unsigned short* bptr1 = wbase + (size_t)(tn * BN + ar1) * DDIM + ac1 * 8;

  __bf16* aw0 = &As[(wave * 32) * BK];
  __bf16* aw1 = &As[(wave * 32 + 16) * BK];
  __bf16* bw0 = &Bs[(wave * 32) * BK];
  __bf16* bw1 = &Bs[(wave * 32 + 16) * BK];

  const int mw = (wave >> 1) * 64;
  const int nw = (wave & 1) * 64;
  const int quad = lane >> 4;
  const int l15 = lane & 15;

  f32x4 acc[4][4] = {};

  for (int kk = 0; kk < DDIM; kk += BK) {
    load_lds16(aptr0, aw0);
    load_lds16(aptr1, aw1);
    load_lds16(bptr0, bw0);
    load_lds16(bptr1, bw1);
    aptr0 += BK; aptr1 += BK; bptr0 += BK; bptr1 += BK;
    __syncthreads();

    bf16x8 af[4], bfr[4];
#pragma unroll
    for (int mi = 0; mi < 4; ++mi) {
      int m = mw + mi * 16 + l15;
      int pos = quad ^ ((m >> 1) & 3);
      af[mi] = *(const bf16x8*)&As[m * BK + pos * 8];
    }
#pragma unroll
    for (int ni = 0; ni < 4; ++ni) {
      int nn = nw + ni * 16 + l15;
      int pos = quad ^ ((nn >> 1) & 3);
      bfr[ni] = *(const bf16x8*)&Bs[nn * BK + pos * 8];
    }
#pragma unroll
    for (int mi = 0; mi < 4; ++mi)
#pragma unroll
      for (int ni = 0; ni < 4; ++ni)
        acc[mi][ni] = __builtin_amdgcn_mfma_f32_16x16x32_bf16(af[mi], bfr[ni], acc[mi][ni], 0, 0, 0);
    __syncthreads();
  }

  const int valid = count - tm * BM;
#pragma unroll
  for (int ni = 0; ni < 4; ++ni) {
    int col = tn * BN + nw + ni * 16 + l15;
    float bias = eb[e * DDIM + col];
#pragma unroll
    for (int mi = 0; mi < 4; ++mi) {
#pragma unroll
      for (int r = 0; r < 4; ++r) {
        int mrow = mw + mi * 16 + quad * 4 + r;
        if (mrow < valid) {
          float v = (acc[mi][ni][r] + bias) * wtS[mrow];
          atomicAdd(out + (size_t)tokS[mrow] * DDIM + col, v);
        }
      }
    }
  }
}

__global__ void loss_kernel(const float* __restrict__ sum_w,
                            const int* __restrict__ cnt,
                            float* __restrict__ out) {
  if (threadIdx.x == 0 && blockIdx.x == 0) {
    float l = 0.0f;
#pragma unroll
    for (int e = 0; e < NEXP; ++e) l += sum_w[e] * (float)cnt[e];
    out[(size_t)N_TOK * DDIM] = l * (1.0f / ((float)N_TOK * (float)N_TOK));
  }
}

extern "C" void kernel_launch(void* const* d_in, const int* in_sizes, int n_in,
                              void* d_out, int out_size, void* d_ws, size_t ws_size,
                              hipStream_t stream) {
  const float* x  = (const float*)d_in[0];
  const float* cv = (const float*)d_in[1];
  const float* rw = (const float*)d_in[2];
  const float* rb = (const float*)d_in[3];
  const float* ew = (const float*)d_in[4];
  const float* eb = (const float*)d_in[5];
  const float* cw = (const float*)d_in[6];
  float* out = (float*)d_out;

  char* ws = (char*)d_ws;
  unsigned short* xg = (unsigned short*)ws;                       // N*D bf16   (33,554,432 B)
  unsigned short* wb = (unsigned short*)(ws + 33554432);          // E*D*D bf16 (16,777,216 B)
  int*   perm_idx = (int*)  (ws + 50331648);                      // E*N int
  float* perm_w   = (float*)(ws + 50855936);                      // E*N float
  int*   cnt      = (int*)  (ws + 51380224);                      // E int
  float* sum_w    = (float*)(ws + 51380256);                      // E float

  hipMemsetAsync(cnt, 0, 64, stream);                             // cnt + sum_w
  hipMemsetAsync(d_out, 0, (size_t)N_TOK * DDIM * sizeof(float), stream);

  cast_w_kernel<<<(NEXP * DDIM * DDIM / 4) / 256, 256, 0, stream>>>(
      (const float4*)ew, (ushort4*)wb);

  router_kernel<<<N_TOK / 4, 256, 0, stream>>>(x, rw, rb, cv, cw,
                                               xg, perm_idx, perm_w, cnt, sum_w);

  moe_gemm_kernel<<<dim3(DDIM / BN, N_TOK / BM, NEXP), 256, 0, stream>>>(
      xg, wb, eb, perm_idx, perm_w, cnt, out);

  loss_kernel<<<1, 64, 0, stream>>>(sum_w, cnt, out);
}

// Round 2
// 359.778 us; speedup vs baseline: 2.1310x; 2.1310x over previous
//
#include <hip/hip_runtime.h>
#include <stdint.h>

#define N_TOK 16384
#define DDIM  1024
#define NEXP  8
#define CNT_STRIDE 64   // pad each counter to its own 256B line

#define BM 128
#define BN 128
#define BK 32

typedef __bf16 bf16x8 __attribute__((ext_vector_type(8)));
typedef float  f32x4  __attribute__((ext_vector_type(4)));

__device__ __forceinline__ unsigned short f2bf(float f) {
  union { float f; uint32_t u; } a; a.f = f;
  uint32_t u = a.u;
  u += 0x7fffu + ((u >> 16) & 1u);   // RNE
  return (unsigned short)(u >> 16);
}

__device__ __forceinline__ void load_lds16(const void* g, void* l) {
  __builtin_amdgcn_global_load_lds(
      (const __attribute__((address_space(1))) void*)g,
      (__attribute__((address_space(3))) void*)l,
      16, 0, 0);
}

// ---- cast expert_w fp32 -> bf16 ----
__global__ __launch_bounds__(256) void cast_w_kernel(const float4* __restrict__ src,
                                                     ushort4* __restrict__ dst) {
  size_t i = (size_t)blockIdx.x * 256 + threadIdx.x;   // E*D*D/4 elements
  float4 v = src[i];
  dst[i] = make_ushort4(f2bf(v.x), f2bf(v.y), f2bf(v.z), f2bf(v.w));
}

// ---- router: logits, softmax, top2, block-aggregated binning, loss partials, x->bf16 ----
// grid 512 blocks x 256 thr; each wave handles 8 tokens; 32 tokens/block.
// Global contended atomics: 8/block (4096 total) on 256B-strided counters.
__global__ __launch_bounds__(256) void router_kernel(
    const float* __restrict__ x, const float* __restrict__ rw,
    const float* __restrict__ rb, const float* __restrict__ cv,
    const float* __restrict__ cwp,
    unsigned short* __restrict__ xg,
    int* __restrict__ perm_idx, float* __restrict__ perm_w,
    int* __restrict__ cnt, float* __restrict__ sum_w)
{
  __shared__ int   sCnt[NEXP];
  __shared__ int   sBase[NEXP];
  __shared__ float sSW[NEXP];
  __shared__ int   sE0[32], sE1[32], sR0[32], sR1[32];
  __shared__ float sW0[32], sW1[32];

  const int tid = threadIdx.x;
  if (tid < NEXP) { sCnt[tid] = 0; sSW[tid] = 0.0f; }
  __syncthreads();

  const int wave = tid >> 6;
  const int lane = tid & 63;

  float lsw[NEXP];
#pragma unroll
  for (int e = 0; e < NEXP; ++e) lsw[e] = 0.0f;

  const float cw = cwp[0];

  for (int t = 0; t < 8; ++t) {
    const int i = wave * 8 + t;                 // token slot in block
    const int n = blockIdx.x * 32 + i;

    float p[NEXP];
#pragma unroll
    for (int e = 0; e < NEXP; ++e) p[e] = 0.0f;

    const float2* x2 = (const float2*)(x + (size_t)n * DDIM);
    uint32_t* xgp = (uint32_t*)(xg + (size_t)n * DDIM);

    // preload the 8 x-chunks (independent loads), then dot against rw (L1-resident)
    float2 xv[8];
#pragma unroll
    for (int it = 0; it < 8; ++it) xv[it] = x2[lane + 64 * it];
#pragma unroll
    for (int it = 0; it < 8; ++it) {
      int dp = lane + 64 * it;
      xgp[dp] = (uint32_t)f2bf(xv[it].x) | ((uint32_t)f2bf(xv[it].y) << 16);
#pragma unroll
      for (int e = 0; e < NEXP; ++e) {
        float2 wv = ((const float2*)(rw + e * DDIM))[dp];
        p[e] = fmaf(xv[it].x, wv.x, fmaf(xv[it].y, wv.y, p[e]));
      }
    }
#pragma unroll
    for (int e = 0; e < NEXP; ++e) {
#pragma unroll
      for (int off = 32; off > 0; off >>= 1)
        p[e] += __shfl_xor(p[e], off, 64);
    }

    if (lane == 0) {
      float w[NEXP];
      float m = -1e30f;
#pragma unroll
      for (int e = 0; e < NEXP; ++e) {
        w[e] = p[e] + rb[e] + cw * cv[e];
        m = fmaxf(m, w[e]);
      }
      float s = 0.0f;
#pragma unroll
      for (int e = 0; e < NEXP; ++e) { w[e] = expf(w[e] - m); s += w[e]; }
      float inv = 1.0f / s;
#pragma unroll
      for (int e = 0; e < NEXP; ++e) { w[e] *= inv; lsw[e] += w[e]; }
      // top-2, ties -> lowest index (matches lax.top_k)
      int e0 = 0;
#pragma unroll
      for (int e = 1; e < NEXP; ++e) if (w[e] > w[e0]) e0 = e;
      int e1 = (e0 == 0) ? 1 : 0;
#pragma unroll
      for (int e = 0; e < NEXP; ++e) if (e != e0 && w[e] > w[e1]) e1 = e;
      float rsum = 1.0f / (w[e0] + w[e1]);
      int r0 = atomicAdd(&sCnt[e0], 1);
      int r1 = atomicAdd(&sCnt[e1], 1);
      sE0[i] = e0; sE1[i] = e1; sR0[i] = r0; sR1[i] = r1;
      sW0[i] = w[e0] * rsum; sW1[i] = w[e1] * rsum;
    }
  }

  if (lane == 0) {
#pragma unroll
    for (int e = 0; e < NEXP; ++e) atomicAdd(&sSW[e], lsw[e]);
  }
  __syncthreads();

  if (tid < NEXP) {
    sBase[tid] = atomicAdd(&cnt[tid * CNT_STRIDE], sCnt[tid]);
    atomicAdd(&sum_w[tid * CNT_STRIDE], sSW[tid]);
  }
  __syncthreads();

  if (tid < 64) {
    int i = tid >> 1, k = tid & 1;
    int e = k ? sE1[i] : sE0[i];
    int r = k ? sR1[i] : sR0[i];
    float wv = k ? sW1[i] : sW0[i];
    int pos = sBase[e] + r;
    int n = blockIdx.x * 32 + i;
    perm_idx[e * N_TOK + pos] = n;
    perm_w [e * N_TOK + pos] = wv;
  }
}

// ---- grouped GEMM: per-expert gathered tokens, bf16 MFMA, weighted scatter ----
__global__ __launch_bounds__(256) void moe_gemm_kernel(
    const unsigned short* __restrict__ xg, const unsigned short* __restrict__ wb,
    const float* __restrict__ eb,
    const int* __restrict__ perm_idx, const float* __restrict__ perm_w,
    const int* __restrict__ cnt, float* __restrict__ out)
{
  const int e = blockIdx.z;
  const int count = cnt[e * CNT_STRIDE];
  const int tm = blockIdx.y;
  if (tm * BM >= count) return;
  const int tn = blockIdx.x;

  __shared__ alignas(16) __bf16 As[BM * BK];
  __shared__ alignas(16) __bf16 Bs[BN * BK];
  __shared__ int   tokS[BM];
  __shared__ float wtS[BM];

  const int tid = threadIdx.x;
  const int wave = tid >> 6;
  const int lane = tid & 63;

  if (tid < BM) {
    int row = tm * BM + tid;
    int rc = row < count ? row : count - 1;
    tokS[tid] = perm_idx[e * N_TOK + rc];
    wtS[tid] = (row < count) ? perm_w[e * N_TOK + row] : 0.0f;
  }
  __syncthreads();

  // staging: each wave covers 32 rows via 2 lane-linear 16B calls of 16 rows.
  // chunk swizzle: chunk c of row m stored at slot c ^ ((m>>1)&3)  -> 2-way-max
  // bank pattern on the b128 fragment reads (free per m136).
  const int slot = lane & 3;
  const int ar0 = wave * 32 + (lane >> 2);
  const int ar1 = ar0 + 16;
  const int ac0 = slot ^ ((ar0 >> 1) & 3);
  const int ac1 = slot ^ ((ar1 >> 1) & 3);

  const unsigned short* aptr0 = xg + (size_t)tokS[ar0] * DDIM + ac0 * 8;
  const unsigned short* aptr1 = xg + (size_t)tokS[ar1] * DDIM + ac1 * 8;
  const unsigned short* wbase = wb + (size_t)e * DDIM * DDIM;
  const unsigned short* bptr0 = wbase + (size_t)(tn * BN + ar0) * DDIM + ac0 * 8;
  const unsigned short* bptr1 = wbase + (size_t)(tn * BN + ar1) * DDIM + ac1 * 8;

  __bf16* aw0 = &As[(wave * 32) * BK];
  __bf16* aw1 = &As[(wave * 32 + 16) * BK];
  __bf16* bw0 = &Bs[(wave * 32) * BK];
  __bf16* bw1 = &Bs[(wave * 32 + 16) * BK];

  const int mw = (wave >> 1) * 64;
  const int nw = (wave & 1) * 64;
  const int quad = lane >> 4;
  const int l15 = lane & 15;

  f32x4 acc[4][4] = {};

  for (int kk = 0; kk < DDIM; kk += BK) {
    load_lds16(aptr0, aw0);
    load_lds16(aptr1, aw1);
    load_lds16(bptr0, bw0);
    load_lds16(bptr1, bw1);
    aptr0 += BK; aptr1 += BK; bptr0 += BK; bptr1 += BK;
    __syncthreads();

    bf16x8 af[4], bfr[4];
#pragma unroll
    for (int mi = 0; mi < 4; ++mi) {
      int m = mw + mi * 16 + l15;
      int pos = quad ^ ((m >> 1) & 3);
      af[mi] = *(const bf16x8*)&As[m * BK + pos * 8];
    }
#pragma unroll
    for (int ni = 0; ni < 4; ++ni) {
      int nn = nw + ni * 16 + l15;
      int pos = quad ^ ((nn >> 1) & 3);
      bfr[ni] = *(const bf16x8*)&Bs[nn * BK + pos * 8];
    }
#pragma unroll
    for (int mi = 0; mi < 4; ++mi)
#pragma unroll
      for (int ni = 0; ni < 4; ++ni)
        acc[mi][ni] = __builtin_amdgcn_mfma_f32_16x16x32_bf16(af[mi], bfr[ni], acc[mi][ni], 0, 0, 0);
    __syncthreads();
  }

  const int valid = count - tm * BM;
#pragma unroll
  for (int ni = 0; ni < 4; ++ni) {
    int col = tn * BN + nw + ni * 16 + l15;
    float bias = eb[e * DDIM + col];
#pragma unroll
    for (int mi = 0; mi < 4; ++mi) {
#pragma unroll
      for (int r = 0; r < 4; ++r) {
        int mrow = mw + mi * 16 + quad * 4 + r;
        if (mrow < valid) {
          float v = (acc[mi][ni][r] + bias) * wtS[mrow];
          atomicAdd(out + (size_t)tokS[mrow] * DDIM + col, v);
        }
      }
    }
  }
}

__global__ void loss_kernel(const float* __restrict__ sum_w,
                            const int* __restrict__ cnt,
                            float* __restrict__ out) {
  if (threadIdx.x == 0 && blockIdx.x == 0) {
    float l = 0.0f;
#pragma unroll
    for (int e = 0; e < NEXP; ++e)
      l += sum_w[e * CNT_STRIDE] * (float)cnt[e * CNT_STRIDE];
    out[(size_t)N_TOK * DDIM] = l * (1.0f / ((float)N_TOK * (float)N_TOK));
  }
}

extern "C" void kernel_launch(void* const* d_in, const int* in_sizes, int n_in,
                              void* d_out, int out_size, void* d_ws, size_t ws_size,
                              hipStream_t stream) {
  const float* x  = (const float*)d_in[0];
  const float* cv = (const float*)d_in[1];
  const float* rw = (const float*)d_in[2];
  const float* rb = (const float*)d_in[3];
  const float* ew = (const float*)d_in[4];
  const float* eb = (const float*)d_in[5];
  const float* cw = (const float*)d_in[6];
  float* out = (float*)d_out;

  char* ws = (char*)d_ws;
  unsigned short* xg = (unsigned short*)ws;                       // N*D bf16   (33,554,432 B)
  unsigned short* wb = (unsigned short*)(ws + 33554432);          // E*D*D bf16 (16,777,216 B)
  int*   perm_idx = (int*)  (ws + 50331648);                      // E*N int
  float* perm_w   = (float*)(ws + 50855936);                      // E*N float
  int*   cnt      = (int*)  (ws + 51380224);                      // E*CNT_STRIDE int   (2048 B)
  float* sum_w    = (float*)(ws + 51382272);                      // E*CNT_STRIDE float (2048 B)

  hipMemsetAsync(cnt, 0, 4096, stream);                           // cnt + sum_w (padded)
  hipMemsetAsync(d_out, 0, (size_t)N_TOK * DDIM * sizeof(float), stream);

  cast_w_kernel<<<(NEXP * DDIM * DDIM / 4) / 256, 256, 0, stream>>>(
      (const float4*)ew, (ushort4*)wb);

  router_kernel<<<N_TOK / 32, 256, 0, stream>>>(x, rw, rb, cv, cw,
                                                xg, perm_idx, perm_w, cnt, sum_w);

  moe_gemm_kernel<<<dim3(DDIM / BN, N_TOK / BM, NEXP), 256, 0, stream>>>(
      xg, wb, eb, perm_idx, perm_w, cnt, out);

  loss_kernel<<<1, 64, 0, stream>>>(sum_w, cnt, out);
}

// Round 3
// 321.939 us; speedup vs baseline: 2.3815x; 1.1175x over previous
//
#include <hip/hip_runtime.h>
#include <stdint.h>

#define N_TOK 16384
#define DDIM  1024
#define NEXP  8
#define CNT_STRIDE 64   // pad each counter to its own 256B line

#define BM 128
#define BN 128
#define BK 32

typedef __bf16 bf16x8 __attribute__((ext_vector_type(8)));
typedef float  f32x4  __attribute__((ext_vector_type(4)));

__device__ __forceinline__ unsigned short f2bf(float f) {
  union { float f; uint32_t u; } a; a.f = f;
  uint32_t u = a.u;
  u += 0x7fffu + ((u >> 16) & 1u);   // RNE
  return (unsigned short)(u >> 16);
}

__device__ __forceinline__ float bf2f(unsigned short u) {
  union { uint32_t u; float f; } a; a.u = ((uint32_t)u) << 16;
  return a.f;
}

__device__ __forceinline__ void load_lds16(const void* g, void* l) {
  __builtin_amdgcn_global_load_lds(
      (const __attribute__((address_space(1))) void*)g,
      (__attribute__((address_space(3))) void*)l,
      16, 0, 0);
}

// ---- cast expert_w fp32 -> bf16 ----
__global__ __launch_bounds__(256) void cast_w_kernel(const float4* __restrict__ src,
                                                     ushort4* __restrict__ dst) {
  size_t i = (size_t)blockIdx.x * 256 + threadIdx.x;   // E*D*D/4 elements
  float4 v = src[i];
  dst[i] = make_ushort4(f2bf(v.x), f2bf(v.y), f2bf(v.z), f2bf(v.w));
}

// ---- router: logits, softmax, top2, block-aggregated binning, loss partials, x->bf16 ----
__global__ __launch_bounds__(256) void router_kernel(
    const float* __restrict__ x, const float* __restrict__ rw,
    const float* __restrict__ rb, const float* __restrict__ cv,
    const float* __restrict__ cwp,
    unsigned short* __restrict__ xg,
    int* __restrict__ perm_idx, float* __restrict__ perm_w,
    int* __restrict__ inv_idx,
    int* __restrict__ cnt, float* __restrict__ sum_w)
{
  __shared__ int   sCnt[NEXP];
  __shared__ int   sBase[NEXP];
  __shared__ float sSW[NEXP];
  __shared__ int   sE0[32], sE1[32], sR0[32], sR1[32];
  __shared__ float sW0[32], sW1[32];

  const int tid = threadIdx.x;
  if (tid < NEXP) { sCnt[tid] = 0; sSW[tid] = 0.0f; }
  __syncthreads();

  const int wave = tid >> 6;
  const int lane = tid & 63;

  float lsw[NEXP];
#pragma unroll
  for (int e = 0; e < NEXP; ++e) lsw[e] = 0.0f;

  const float cw = cwp[0];

  for (int t = 0; t < 8; ++t) {
    const int i = wave * 8 + t;                 // token slot in block
    const int n = blockIdx.x * 32 + i;

    float p[NEXP];
#pragma unroll
    for (int e = 0; e < NEXP; ++e) p[e] = 0.0f;

    const float2* x2 = (const float2*)(x + (size_t)n * DDIM);
    uint32_t* xgp = (uint32_t*)(xg + (size_t)n * DDIM);

    float2 xv[8];
#pragma unroll
    for (int it = 0; it < 8; ++it) xv[it] = x2[lane + 64 * it];
#pragma unroll
    for (int it = 0; it < 8; ++it) {
      int dp = lane + 64 * it;
      xgp[dp] = (uint32_t)f2bf(xv[it].x) | ((uint32_t)f2bf(xv[it].y) << 16);
#pragma unroll
      for (int e = 0; e < NEXP; ++e) {
        float2 wv = ((const float2*)(rw + e * DDIM))[dp];
        p[e] = fmaf(xv[it].x, wv.x, fmaf(xv[it].y, wv.y, p[e]));
      }
    }
#pragma unroll
    for (int e = 0; e < NEXP; ++e) {
#pragma unroll
      for (int off = 32; off > 0; off >>= 1)
        p[e] += __shfl_xor(p[e], off, 64);
    }

    if (lane == 0) {
      float w[NEXP];
      float m = -1e30f;
#pragma unroll
      for (int e = 0; e < NEXP; ++e) {
        w[e] = p[e] + rb[e] + cw * cv[e];
        m = fmaxf(m, w[e]);
      }
      float s = 0.0f;
#pragma unroll
      for (int e = 0; e < NEXP; ++e) { w[e] = expf(w[e] - m); s += w[e]; }
      float inv = 1.0f / s;
#pragma unroll
      for (int e = 0; e < NEXP; ++e) { w[e] *= inv; lsw[e] += w[e]; }
      int e0 = 0;
#pragma unroll
      for (int e = 1; e < NEXP; ++e) if (w[e] > w[e0]) e0 = e;
      int e1 = (e0 == 0) ? 1 : 0;
#pragma unroll
      for (int e = 0; e < NEXP; ++e) if (e != e0 && w[e] > w[e1]) e1 = e;
      float rsum = 1.0f / (w[e0] + w[e1]);
      int r0 = atomicAdd(&sCnt[e0], 1);
      int r1 = atomicAdd(&sCnt[e1], 1);
      sE0[i] = e0; sE1[i] = e1; sR0[i] = r0; sR1[i] = r1;
      sW0[i] = w[e0] * rsum; sW1[i] = w[e1] * rsum;
    }
  }

  if (lane == 0) {
#pragma unroll
    for (int e = 0; e < NEXP; ++e) atomicAdd(&sSW[e], lsw[e]);
  }
  __syncthreads();

  if (tid < NEXP) {
    sBase[tid] = atomicAdd(&cnt[tid * CNT_STRIDE], sCnt[tid]);
    atomicAdd(&sum_w[tid * CNT_STRIDE], sSW[tid]);
  }
  __syncthreads();

  if (tid < 64) {
    int i = tid >> 1, k = tid & 1;
    int e = k ? sE1[i] : sE0[i];
    int r = k ? sR1[i] : sR0[i];
    float wv = k ? sW1[i] : sW0[i];
    int pos = sBase[e] + r;
    int n = blockIdx.x * 32 + i;
    perm_idx[e * N_TOK + pos] = n;
    perm_w [e * N_TOK + pos] = wv;
    inv_idx[2 * n + k] = (e << 14) | pos;     // pos < 16384 fits 14 bits
  }
}

// ---- grouped GEMM ----
// grid (tm=x, tn=y, e=z): all 8 tn-tiles of one A-tile land on XCD (tm%8) -> A-fetch x8 less.
// MODE 0: atomicAdd into f32 out (fallback). MODE 1: plain bf16 store of w*(y+b) into
// compact permuted ybuf (row = expertBase[e] + position), combined by combine_kernel.
template<int MODE>
__global__ __launch_bounds__(256) void moe_gemm_kernel(
    const unsigned short* __restrict__ xg, const unsigned short* __restrict__ wb,
    const float* __restrict__ eb,
    const int* __restrict__ perm_idx, const float* __restrict__ perm_w,
    const int* __restrict__ cnt,
    unsigned short* __restrict__ ybuf, float* __restrict__ out)
{
  const int e = blockIdx.z;
  const int count = cnt[e * CNT_STRIDE];
  const int tm = blockIdx.x;
  if (tm * BM >= count) return;
  const int tn = blockIdx.y;

  __shared__ alignas(16) __bf16 As[BM * BK];
  __shared__ alignas(16) __bf16 Bs[BN * BK];
  __shared__ int   tokS[BM];
  __shared__ float wtS[BM];

  const int tid = threadIdx.x;
  const int wave = tid >> 6;
  const int lane = tid & 63;

  if (tid < BM) {
    int row = tm * BM + tid;
    int rc = row < count ? row : count - 1;
    tokS[tid] = perm_idx[e * N_TOK + rc];
    wtS[tid] = (row < count) ? perm_w[e * N_TOK + row] : 0.0f;
  }
  __syncthreads();

  const int slot = lane & 3;
  const int ar0 = wave * 32 + (lane >> 2);
  const int ar1 = ar0 + 16;
  const int ac0 = slot ^ ((ar0 >> 1) & 3);
  const int ac1 = slot ^ ((ar1 >> 1) & 3);

  const unsigned short* aptr0 = xg + (size_t)tokS[ar0] * DDIM + ac0 * 8;
  const unsigned short* aptr1 = xg + (size_t)tokS[ar1] * DDIM + ac1 * 8;
  const unsigned short* wbase = wb + (size_t)e * DDIM * DDIM;
  const unsigned short* bptr0 = wbase + (size_t)(tn * BN + ar0) * DDIM + ac0 * 8;
  const unsigned short* bptr1 = wbase + (size_t)(tn * BN + ar1) * DDIM + ac1 * 8;

  __bf16* aw0 = &As[(wave * 32) * BK];
  __bf16* aw1 = &As[(wave * 32 + 16) * BK];
  __bf16* bw0 = &Bs[(wave * 32) * BK];
  __bf16* bw1 = &Bs[(wave * 32 + 16) * BK];

  const int mw = (wave >> 1) * 64;
  const int nw = (wave & 1) * 64;
  const int quad = lane >> 4;
  const int l15 = lane & 15;

  f32x4 acc[4][4] = {};

  for (int kk = 0; kk < DDIM; kk += BK) {
    load_lds16(aptr0, aw0);
    load_lds16(aptr1, aw1);
    load_lds16(bptr0, bw0);
    load_lds16(bptr1, bw1);
    aptr0 += BK; aptr1 += BK; bptr0 += BK; bptr1 += BK;
    __syncthreads();

    bf16x8 af[4], bfr[4];
#pragma unroll
    for (int mi = 0; mi < 4; ++mi) {
      int m = mw + mi * 16 + l15;
      int pos = quad ^ ((m >> 1) & 3);
      af[mi] = *(const bf16x8*)&As[m * BK + pos * 8];
    }
#pragma unroll
    for (int ni = 0; ni < 4; ++ni) {
      int nn = nw + ni * 16 + l15;
      int pos = quad ^ ((nn >> 1) & 3);
      bfr[ni] = *(const bf16x8*)&Bs[nn * BK + pos * 8];
    }
#pragma unroll
    for (int mi = 0; mi < 4; ++mi)
#pragma unroll
      for (int ni = 0; ni < 4; ++ni)
        acc[mi][ni] = __builtin_amdgcn_mfma_f32_16x16x32_bf16(af[mi], bfr[ni], acc[mi][ni], 0, 0, 0);
    __syncthreads();
  }

  int ebase = 0;
  if (MODE == 1) {
#pragma unroll
    for (int j = 0; j < NEXP; ++j) if (j < e) ebase += cnt[j * CNT_STRIDE];
  }

  const int valid = count - tm * BM;
#pragma unroll
  for (int ni = 0; ni < 4; ++ni) {
    int col = tn * BN + nw + ni * 16 + l15;
    float bias = eb[e * DDIM + col];
#pragma unroll
    for (int mi = 0; mi < 4; ++mi) {
#pragma unroll
      for (int r = 0; r < 4; ++r) {
        int mrow = mw + mi * 16 + quad * 4 + r;
        if (mrow < valid) {
          float v = (acc[mi][ni][r] + bias) * wtS[mrow];
          if (MODE == 1) {
            ybuf[(size_t)(ebase + tm * BM + mrow) * DDIM + col] = f2bf(v);
          } else {
            atomicAdd(out + (size_t)tokS[mrow] * DDIM + col, v);
          }
        }
      }
    }
  }
}

// ---- combine: out[n] = y[g0] + y[g1] (weights+bias already folded) ----
__global__ __launch_bounds__(256) void combine_kernel(
    const unsigned short* __restrict__ ybuf, const int* __restrict__ inv_idx,
    const int* __restrict__ cnt, float* __restrict__ out)
{
  const int wave = threadIdx.x >> 6;
  const int lane = threadIdx.x & 63;
  const int n = blockIdx.x * 4 + wave;

  int base[NEXP];
  int acc = 0;
#pragma unroll
  for (int j = 0; j < NEXP; ++j) { base[j] = acc; acc += cnt[j * CNT_STRIDE]; }

  int i0 = inv_idx[2 * n];
  int i1 = inv_idx[2 * n + 1];
  int g0 = base[i0 >> 14] + (i0 & 16383);
  int g1 = base[i1 >> 14] + (i1 & 16383);

  const ushort4* r0 = (const ushort4*)(ybuf + (size_t)g0 * DDIM);
  const ushort4* r1 = (const ushort4*)(ybuf + (size_t)g1 * DDIM);
  float4* o = (float4*)(out + (size_t)n * DDIM);

#pragma unroll
  for (int it = 0; it < 4; ++it) {
    int c = lane + 64 * it;
    ushort4 a = r0[c];
    ushort4 b = r1[c];
    float4 v;
    v.x = bf2f(a.x) + bf2f(b.x);
    v.y = bf2f(a.y) + bf2f(b.y);
    v.z = bf2f(a.z) + bf2f(b.z);
    v.w = bf2f(a.w) + bf2f(b.w);
    o[c] = v;
  }
}

__global__ void loss_kernel(const float* __restrict__ sum_w,
                            const int* __restrict__ cnt,
                            float* __restrict__ out) {
  if (threadIdx.x == 0 && blockIdx.x == 0) {
    float l = 0.0f;
#pragma unroll
    for (int e = 0; e < NEXP; ++e)
      l += sum_w[e * CNT_STRIDE] * (float)cnt[e * CNT_STRIDE];
    out[(size_t)N_TOK * DDIM] = l * (1.0f / ((float)N_TOK * (float)N_TOK));
  }
}

extern "C" void kernel_launch(void* const* d_in, const int* in_sizes, int n_in,
                              void* d_out, int out_size, void* d_ws, size_t ws_size,
                              hipStream_t stream) {
  const float* x  = (const float*)d_in[0];
  const float* cv = (const float*)d_in[1];
  const float* rw = (const float*)d_in[2];
  const float* rb = (const float*)d_in[3];
  const float* ew = (const float*)d_in[4];
  const float* eb = (const float*)d_in[5];
  const float* cw = (const float*)d_in[6];
  float* out = (float*)d_out;

  char* ws = (char*)d_ws;
  unsigned short* xg = (unsigned short*)ws;                       // N*D bf16   (33,554,432 B)
  unsigned short* wb = (unsigned short*)(ws + 33554432);          // E*D*D bf16 (16,777,216 B)
  int*   perm_idx = (int*)  (ws + 50331648);                      // E*N int    (524,288 B)
  float* perm_w   = (float*)(ws + 50855936);                      // E*N float  (524,288 B)
  int*   inv_idx  = (int*)  (ws + 51380224);                      // 2*N int    (131,072 B)
  int*   cnt      = (int*)  (ws + 51511296);                      // padded     (2,048 B)
  float* sum_w    = (float*)(ws + 51513344);                      // padded     (2,048 B)
  unsigned short* ybuf = (unsigned short*)(ws + 51515392);        // 2*N*D bf16 (67,108,864 B)
  const size_t NEED = 51515392ull + 67108864ull;

  const bool big = ws_size >= NEED;

  hipMemsetAsync(cnt, 0, 4096, stream);                           // cnt + sum_w (padded)
  if (!big)
    hipMemsetAsync(d_out, 0, (size_t)N_TOK * DDIM * sizeof(float), stream);

  cast_w_kernel<<<(NEXP * DDIM * DDIM / 4) / 256, 256, 0, stream>>>(
      (const float4*)ew, (ushort4*)wb);

  router_kernel<<<N_TOK / 32, 256, 0, stream>>>(x, rw, rb, cv, cw,
                                                xg, perm_idx, perm_w, inv_idx, cnt, sum_w);

  if (big) {
    moe_gemm_kernel<1><<<dim3(N_TOK / BM, DDIM / BN, NEXP), 256, 0, stream>>>(
        xg, wb, eb, perm_idx, perm_w, cnt, ybuf, out);
    combine_kernel<<<N_TOK / 4, 256, 0, stream>>>(ybuf, inv_idx, cnt, out);
  } else {
    moe_gemm_kernel<0><<<dim3(N_TOK / BM, DDIM / BN, NEXP), 256, 0, stream>>>(
        xg, wb, eb, perm_idx, perm_w, cnt, ybuf, out);
  }

  loss_kernel<<<1, 64, 0, stream>>>(sum_w, cnt, out);
}

// Round 5
// 291.993 us; speedup vs baseline: 2.6257x; 1.1026x over previous
//
#include <hip/hip_runtime.h>
#include <stdint.h>

#define N_TOK 16384
#define DDIM  1024
#define NEXP  8
#define CNT_STRIDE 64   // pad each counter to its own 256B line

#define BM 128
#define BN 128
#define BK 64
#define MAX_TILES 264   // sum ceil(cnt_e/128) <= 32768/128 + 8
#define EP_PITCH 72     // epilogue LDS row pitch in ushorts (144B: 16B-aligned, bank-spread)

typedef __bf16 bf16x8 __attribute__((ext_vector_type(8)));
typedef float  f32x4  __attribute__((ext_vector_type(4)));

__device__ __forceinline__ unsigned short f2bf(float f) {
  union { float f; uint32_t u; } a; a.f = f;
  uint32_t u = a.u;
  u += 0x7fffu + ((u >> 16) & 1u);   // RNE
  return (unsigned short)(u >> 16);
}

__device__ __forceinline__ float bf2f(unsigned short u) {
  union { uint32_t u; float f; } a; a.u = ((uint32_t)u) << 16;
  return a.f;
}

__device__ __forceinline__ float2 bfpair(uint32_t u) {
  union { uint32_t u; float f; } lo, hi;
  lo.u = u << 16; hi.u = u & 0xffff0000u;
  return make_float2(lo.f, hi.f);
}

__device__ __forceinline__ void load_lds16(const void* g, void* l) {
  __builtin_amdgcn_global_load_lds(
      (const __attribute__((address_space(1))) void*)g,
      (__attribute__((address_space(3))) void*)l,
      16, 0, 0);
}

// ---- router: logits, softmax, top2, block-aggregated binning, loss partials,
//      x->bf16 cast, and fused expert_w->bf16 cast.
// 512 thr = 8 waves x 4 tokens; grid 512 blocks (32 tokens/block).
__global__ __launch_bounds__(512) void router_kernel(
    const float* __restrict__ x, const float* __restrict__ rw,
    const float* __restrict__ rb, const float* __restrict__ cv,
    const float* __restrict__ cwp,
    const float4* __restrict__ ew4, ushort4* __restrict__ wb4,
    unsigned short* __restrict__ xg,
    int* __restrict__ perm_idx, float* __restrict__ perm_w,
    int* __restrict__ inv_idx,
    int* __restrict__ cnt, float* __restrict__ sum_w)
{
  __shared__ int   sCnt[NEXP];
  __shared__ int   sBase[NEXP];
  __shared__ float sSW[NEXP];
  __shared__ int   sE0[32], sE1[32], sR0[32], sR1[32];
  __shared__ float sW0[32], sW1[32];

  const int tid = threadIdx.x;
  if (tid < NEXP) { sCnt[tid] = 0; sSW[tid] = 0.0f; }
  __syncthreads();

  const int wave = tid >> 6;     // 0..7
  const int lane = tid & 63;

  float lsw[NEXP];
#pragma unroll
  for (int e = 0; e < NEXP; ++e) lsw[e] = 0.0f;

  const float cw = cwp[0];

  for (int t = 0; t < 4; ++t) {
    const int i = wave * 4 + t;                 // token slot in block (0..31)
    const int n = blockIdx.x * 32 + i;

    float p[NEXP];
#pragma unroll
    for (int e = 0; e < NEXP; ++e) p[e] = 0.0f;

    const float2* x2 = (const float2*)(x + (size_t)n * DDIM);
    uint32_t* xgp = (uint32_t*)(xg + (size_t)n * DDIM);

    float2 xv[8];
#pragma unroll
    for (int it = 0; it < 8; ++it) xv[it] = x2[lane + 64 * it];
#pragma unroll
    for (int it = 0; it < 8; ++it) {
      int dp = lane + 64 * it;
      xgp[dp] = (uint32_t)f2bf(xv[it].x) | ((uint32_t)f2bf(xv[it].y) << 16);
#pragma unroll
      for (int e = 0; e < NEXP; ++e) {
        float2 wv = ((const float2*)(rw + e * DDIM))[dp];
        p[e] = fmaf(xv[it].x, wv.x, fmaf(xv[it].y, wv.y, p[e]));
      }
    }
#pragma unroll
    for (int e = 0; e < NEXP; ++e) {
#pragma unroll
      for (int off = 32; off > 0; off >>= 1)
        p[e] += __shfl_xor(p[e], off, 64);
    }

    if (lane == 0) {
      float w[NEXP];
      float m = -1e30f;
#pragma unroll
      for (int e = 0; e < NEXP; ++e) {
        w[e] = p[e] + rb[e] + cw * cv[e];
        m = fmaxf(m, w[e]);
      }
      float s = 0.0f;
#pragma unroll
      for (int e = 0; e < NEXP; ++e) { w[e] = expf(w[e] - m); s += w[e]; }
      float inv = 1.0f / s;
#pragma unroll
      for (int e = 0; e < NEXP; ++e) { w[e] *= inv; lsw[e] += w[e]; }
      int e0 = 0;
#pragma unroll
      for (int e = 1; e < NEXP; ++e) if (w[e] > w[e0]) e0 = e;
      int e1 = (e0 == 0) ? 1 : 0;
#pragma unroll
      for (int e = 0; e < NEXP; ++e) if (e != e0 && w[e] > w[e1]) e1 = e;
      float rsum = 1.0f / (w[e0] + w[e1]);
      int r0 = atomicAdd(&sCnt[e0], 1);
      int r1 = atomicAdd(&sCnt[e1], 1);
      sE0[i] = e0; sE1[i] = e1; sR0[i] = r0; sR1[i] = r1;
      sW0[i] = w[e0] * rsum; sW1[i] = w[e1] * rsum;
    }
  }

  if (lane == 0) {
#pragma unroll
    for (int e = 0; e < NEXP; ++e) atomicAdd(&sSW[e], lsw[e]);
  }
  __syncthreads();

  if (tid < NEXP) {
    sBase[tid] = atomicAdd(&cnt[tid * CNT_STRIDE], sCnt[tid]);
    atomicAdd(&sum_w[tid * CNT_STRIDE], sSW[tid]);
  }
  __syncthreads();

  if (tid < 64) {
    int i = tid >> 1, k = tid & 1;
    int e = k ? sE1[i] : sE0[i];
    int r = k ? sR1[i] : sR0[i];
    float wv = k ? sW1[i] : sW0[i];
    int pos = sBase[e] + r;
    int n = blockIdx.x * 32 + i;
    perm_idx[e * N_TOK + pos] = n;
    perm_w [e * N_TOK + pos] = wv;
    inv_idx[2 * n + k] = (e << 14) | pos;     // pos < 16384 fits 14 bits
  }

  // fused expert_w fp32->bf16 cast: E*D*D/4 = 2,097,152 float4 over
  // 512 blocks x 512 threads = 262,144 threads -> exactly 8 each.
  size_t base = (size_t)blockIdx.x * 512 + tid;
#pragma unroll
  for (int i2 = 0; i2 < 8; ++i2) {
    size_t idx = base + (size_t)i2 * 262144;
    float4 v = ew4[idx];
    wb4[idx] = make_ushort4(f2bf(v.x), f2bf(v.y), f2bf(v.z), f2bf(v.w));
  }
}

// ---- grouped GEMM, BK=64, transposed MFMA, LDS-repacked coalesced epilogue ----
// Flat grid of MAX_TILES*8 blocks; id = tileIdx + MAX_TILES*tn so the 8 tn-blocks
// sharing one A-tile have ids congruent mod 8 -> same XCD (A-fetch co-location).
template<int MODE>
__global__ __launch_bounds__(256) void moe_gemm_kernel(
    const unsigned short* __restrict__ xg, const unsigned short* __restrict__ wb,
    const float* __restrict__ eb,
    const int* __restrict__ perm_idx, const float* __restrict__ perm_w,
    const int* __restrict__ cnt,
    unsigned short* __restrict__ ybuf, float* __restrict__ out)
{
  const int id = blockIdx.x;
  const int tn = id / MAX_TILES;
  const int tileIdx = id - tn * MAX_TILES;

  int e = -1, tm = 0, count = 0, ebase = 0, pref = 0;
#pragma unroll
  for (int j = 0; j < NEXP; ++j) {
    int c = cnt[j * CNT_STRIDE];
    int t = (c + BM - 1) >> 7;
    if (e < 0 && tileIdx < pref + t) { e = j; tm = tileIdx - pref; count = c; }
    if (e < 0) ebase += c;
    pref += t;
  }
  if (e < 0) return;

  __shared__ union {
    struct { __bf16 As[BM * BK]; __bf16 Bs[BN * BK]; } g;   // 16KB + 16KB
    __bf16 ep[4 * 64 * EP_PITCH];                           // 4 slabs x 9216B
  } sm;
  __shared__ int   tokS[BM];
  __shared__ float wtS[BM];

  const int tid = threadIdx.x;
  const int wave = tid >> 6;
  const int lane = tid & 63;

  if (tid < BM) {
    int row = tm * BM + tid;
    int rc = row < count ? row : count - 1;
    tokS[tid] = perm_idx[e * N_TOK + rc];
    wtS[tid] = (row < count) ? perm_w[e * N_TOK + row] : 0.0f;
  }
  __syncthreads();

  // staging: wave covers 32 rows (4 calls x 8 rows). lane -> row wave*32+t*8+(l>>3),
  // slot s=l&7; LDS[r][s] holds global chunk s^(r&7)  (chunk = 16B of the 128B row).
  const unsigned short* aptr[4];
  const unsigned short* bptr[4];
  const unsigned short* wbase = wb + (size_t)e * DDIM * DDIM;
#pragma unroll
  for (int t = 0; t < 4; ++t) {
    int r = wave * 32 + t * 8 + (lane >> 3);
    int cg = (lane & 7) ^ (r & 7);
    aptr[t] = xg + (size_t)tokS[r] * DDIM + cg * 8;
    bptr[t] = wbase + (size_t)(tn * BN + r) * DDIM + cg * 8;
  }

  const int mw = (wave >> 1) * 64;
  const int nw = (wave & 1) * 64;
  const int quad = lane >> 4;
  const int l15 = lane & 15;

  f32x4 acc[4][4] = {};   // acc[mi][ni]: rows mw+mi*16+l15, cols nw+ni*16+quad*4+reg

  for (int kk = 0; kk < DDIM; kk += BK) {
#pragma unroll
    for (int t = 0; t < 4; ++t) {
      load_lds16(aptr[t], &sm.g.As[(wave * 32 + t * 8) * BK]);
      load_lds16(bptr[t], &sm.g.Bs[(wave * 32 + t * 8) * BK]);
      aptr[t] += BK; bptr[t] += BK;
    }
    __syncthreads();

#pragma unroll
    for (int ks = 0; ks < 2; ++ks) {
      bf16x8 af[4], bfr[4];
#pragma unroll
      for (int mi = 0; mi < 4; ++mi) {
        int m = mw + mi * 16 + l15;
        int slot = (ks * 4 + quad) ^ (m & 7);
        af[mi] = *(const bf16x8*)&sm.g.As[m * BK + slot * 8];
      }
#pragma unroll
      for (int ni = 0; ni < 4; ++ni) {
        int n = nw + ni * 16 + l15;
        int slot = (ks * 4 + quad) ^ (n & 7);
        bfr[ni] = *(const bf16x8*)&sm.g.Bs[n * BK + slot * 8];
      }
#pragma unroll
      for (int mi = 0; mi < 4; ++mi)
#pragma unroll
        for (int ni = 0; ni < 4; ++ni)
          // swapped operands: D^T -> l15 indexes token row, quad*4+reg indexes col
          acc[mi][ni] = __builtin_amdgcn_mfma_f32_16x16x32_bf16(bfr[ni], af[mi], acc[mi][ni], 0, 0, 0);
    }
    __syncthreads();
  }

  const int valid = count - tm * BM;

  if (MODE == 1) {
    // repack through per-wave LDS slab, then fully-coalesced 16B stores
    __bf16* slab = &sm.ep[wave * (64 * EP_PITCH)];
#pragma unroll
    for (int mi = 0; mi < 4; ++mi) {
      float wt = wtS[mw + mi * 16 + l15];
#pragma unroll
      for (int ni = 0; ni < 4; ++ni) {
        int gcol = tn * BN + nw + ni * 16 + quad * 4;
        const float4 bv = *(const float4*)&eb[e * DDIM + gcol];
        ushort4 pk;
        pk.x = f2bf((acc[mi][ni][0] + bv.x) * wt);
        pk.y = f2bf((acc[mi][ni][1] + bv.y) * wt);
        pk.z = f2bf((acc[mi][ni][2] + bv.z) * wt);
        pk.w = f2bf((acc[mi][ni][3] + bv.w) * wt);
        *(ushort4*)&slab[(mi * 16 + l15) * EP_PITCH + ni * 16 + quad * 4] = pk;
      }
    }
    const int gb = ebase + tm * BM;
#pragma unroll
    for (int s = 0; s < 8; ++s) {
      int lrow = s * 8 + (lane >> 3);
      uint4 v = *(const uint4*)&slab[lrow * EP_PITCH + (lane & 7) * 8];
      int brow = mw + lrow;
      if (brow < valid)
        *(uint4*)&ybuf[(size_t)(gb + brow) * DDIM + tn * BN + nw + (lane & 7) * 8] = v;
    }
  } else {
    // atomic fallback (small-ws path)
#pragma unroll
    for (int mi = 0; mi < 4; ++mi) {
      int brow = mw + mi * 16 + l15;
      float wt = wtS[brow];
      int tok = tokS[brow];
#pragma unroll
      for (int ni = 0; ni < 4; ++ni) {
        int gcol = tn * BN + nw + ni * 16 + quad * 4;
        const float4 bv = *(const float4*)&eb[e * DDIM + gcol];
        if (brow < valid) {
          atomicAdd(out + (size_t)tok * DDIM + gcol + 0, (acc[mi][ni][0] + bv.x) * wt);
          atomicAdd(out + (size_t)tok * DDIM + gcol + 1, (acc[mi][ni][1] + bv.y) * wt);
          atomicAdd(out + (size_t)tok * DDIM + gcol + 2, (acc[mi][ni][2] + bv.z) * wt);
          atomicAdd(out + (size_t)tok * DDIM + gcol + 3, (acc[mi][ni][3] + bv.w) * wt);
        }
      }
    }
  }
}

// ---- combine: out[n] = y[g0] + y[g1] (weights+bias already folded) ----
__global__ __launch_bounds__(256) void combine_kernel(
    const unsigned short* __restrict__ ybuf, const int* __restrict__ inv_idx,
    const int* __restrict__ cnt, float* __restrict__ out)
{
  const int wave = threadIdx.x >> 6;
  const int lane = threadIdx.x & 63;
  const int n = blockIdx.x * 4 + wave;

  int base[NEXP];
  int acc = 0;
#pragma unroll
  for (int j = 0; j < NEXP; ++j) { base[j] = acc; acc += cnt[j * CNT_STRIDE]; }

  int i0 = inv_idx[2 * n];
  int i1 = inv_idx[2 * n + 1];
  int g0 = base[i0 >> 14] + (i0 & 16383);
  int g1 = base[i1 >> 14] + (i1 & 16383);

  const uint4* r0 = (const uint4*)(ybuf + (size_t)g0 * DDIM);
  const uint4* r1 = (const uint4*)(ybuf + (size_t)g1 * DDIM);
  float4* o = (float4*)(out + (size_t)n * DDIM);

#pragma unroll
  for (int it = 0; it < 2; ++it) {
    int c = lane + 64 * it;
    uint4 a = r0[c];
    uint4 b = r1[c];
    float2 a0 = bfpair(a.x), a1 = bfpair(a.y), a2 = bfpair(a.z), a3 = bfpair(a.w);
    float2 b0 = bfpair(b.x), b1 = bfpair(b.y), b2 = bfpair(b.z), b3 = bfpair(b.w);
    float4 v0, v1;
    v0.x = a0.x + b0.x; v0.y = a0.y + b0.y; v0.z = a1.x + b1.x; v0.w = a1.y + b1.y;
    v1.x = a2.x + b2.x; v1.y = a2.y + b2.y; v1.z = a3.x + b3.x; v1.w = a3.y + b3.y;
    o[2 * c] = v0;
    o[2 * c + 1] = v1;
  }
}

__global__ void loss_kernel(const float* __restrict__ sum_w,
                            const int* __restrict__ cnt,
                            float* __restrict__ out) {
  if (threadIdx.x == 0 && blockIdx.x == 0) {
    float l = 0.0f;
#pragma unroll
    for (int e = 0; e < NEXP; ++e)
      l += sum_w[e * CNT_STRIDE] * (float)cnt[e * CNT_STRIDE];
    out[(size_t)N_TOK * DDIM] = l * (1.0f / ((float)N_TOK * (float)N_TOK));
  }
}

extern "C" void kernel_launch(void* const* d_in, const int* in_sizes, int n_in,
                              void* d_out, int out_size, void* d_ws, size_t ws_size,
                              hipStream_t stream) {
  const float* x  = (const float*)d_in[0];
  const float* cv = (const float*)d_in[1];
  const float* rw = (const float*)d_in[2];
  const float* rb = (const float*)d_in[3];
  const float* ew = (const float*)d_in[4];
  const float* eb = (const float*)d_in[5];
  const float* cw = (const float*)d_in[6];
  float* out = (float*)d_out;

  char* ws = (char*)d_ws;
  unsigned short* xg = (unsigned short*)ws;                       // N*D bf16   (33,554,432 B)
  unsigned short* wb = (unsigned short*)(ws + 33554432);          // E*D*D bf16 (16,777,216 B)
  int*   perm_idx = (int*)  (ws + 50331648);                      // E*N int    (524,288 B)
  float* perm_w   = (float*)(ws + 50855936);                      // E*N float  (524,288 B)
  int*   inv_idx  = (int*)  (ws + 51380224);                      // 2*N int    (131,072 B)
  int*   cnt      = (int*)  (ws + 51511296);                      // padded     (2,048 B)
  float* sum_w    = (float*)(ws + 51513344);                      // padded     (2,048 B)
  unsigned short* ybuf = (unsigned short*)(ws + 51515392);        // 2*N*D bf16 (67,108,864 B)
  const size_t NEED = 51515392ull + 67108864ull;

  const bool big = ws_size >= NEED;

  hipMemsetAsync(cnt, 0, 4096, stream);                           // cnt + sum_w (padded)
  if (!big)
    hipMemsetAsync(d_out, 0, (size_t)N_TOK * DDIM * sizeof(float), stream);

  router_kernel<<<N_TOK / 32, 512, 0, stream>>>(x, rw, rb, cv, cw,
                                                (const float4*)ew, (ushort4*)wb,
                                                xg, perm_idx, perm_w, inv_idx, cnt, sum_w);

  if (big) {
    moe_gemm_kernel<1><<<MAX_TILES * 8, 256, 0, stream>>>(
        xg, wb, eb, perm_idx, perm_w, cnt, ybuf, out);
    combine_kernel<<<N_TOK / 4, 256, 0, stream>>>(ybuf, inv_idx, cnt, out);
  } else {
    moe_gemm_kernel<0><<<MAX_TILES * 8, 256, 0, stream>>>(
        xg, wb, eb, perm_idx, perm_w, cnt, ybuf, out);
  }

  loss_kernel<<<1, 64, 0, stream>>>(sum_w, cnt, out);
}